// Round 1
// baseline (32.285 us; speedup 1.0000x reference)
//
#include <hip/hip_runtime.h>
#include <math.h>

#define TCH 256  // train points staged per LDS tile (256 * 64B = 16 KB)

// Each thread owns one test point (16 f32 in VGPRs, pre-scaled by log2(e)).
// Block stages TCH train points into LDS; inner loop is a wave-uniform
// broadcast read + 16 FMA dot product + v_exp_f32 accumulate.
// writeFinal==1: write log(sum)-Z directly to out (S==1 fallback path).
// writeFinal==0: write partial sum to ws[blockIdx.y * nTest + ti].
__global__ __launch_bounds__(256) void kde_partial(
    const float* __restrict__ testX, const float* __restrict__ trainX,
    float* __restrict__ wsOrOut, int nTest, int nTrain, int trainPer,
    int writeFinal, float Z)
{
    __shared__ float4 sT[TCH * 4];
    __shared__ float  sN[TCH];

    const float LOG2E = 1.4426950408889634f;
    const int tid = threadIdx.x;
    const int ti  = blockIdx.x * 256 + tid;
    const bool valid = ti < nTest;

    // Load test point, scale by log2e so exp(arg) == exp2(arg').
    float x[16];
    float xn2p = 0.0f;
    if (valid) {
        #pragma unroll
        for (int k = 0; k < 4; ++k) {
            float4 v = ((const float4*)testX)[ti * 4 + k];
            x[4*k+0] = v.x * LOG2E;
            x[4*k+1] = v.y * LOG2E;
            x[4*k+2] = v.z * LOG2E;
            x[4*k+3] = v.w * LOG2E;
        }
        float xn = 0.0f;
        #pragma unroll
        for (int d = 0; d < 16; ++d) xn = fmaf(x[d], x[d], xn);
        // xn = log2e^2 * ||x||^2  ->  0.5*log2e*||x||^2 = xn * 0.5/log2e
        xn2p = xn * (0.5f / LOG2E);
    } else {
        #pragma unroll
        for (int d = 0; d < 16; ++d) x[d] = 0.0f;
    }

    const int trainBegin = blockIdx.y * trainPer;
    const int trainEnd   = min(nTrain, trainBegin + trainPer);

    float acc = 0.0f;
    for (int t0 = trainBegin; t0 < trainEnd; t0 += TCH) {
        const int cnt = min(TCH, trainEnd - t0);
        __syncthreads();  // protect sT reuse from previous tile
        // Stage cnt train points (cnt*4 float4s), coalesced.
        for (int idx = tid; idx < cnt * 4; idx += 256)
            sT[idx] = ((const float4*)trainX)[t0 * 4 + idx];
        __syncthreads();
        // Precompute 0.5*log2e*||y||^2 per staged train point.
        for (int j = tid; j < cnt; j += 256) {
            float4 a = sT[j*4+0], b = sT[j*4+1], c = sT[j*4+2], e = sT[j*4+3];
            float n = a.x*a.x + a.y*a.y + a.z*a.z + a.w*a.w
                    + b.x*b.x + b.y*b.y + b.z*b.z + b.w*b.w
                    + c.x*c.x + c.y*c.y + c.z*c.z + c.w*c.w
                    + e.x*e.x + e.y*e.y + e.z*e.z + e.w*e.w;
            sN[j] = n * (0.5f * LOG2E);
        }
        __syncthreads();

        #pragma unroll 2
        for (int j = 0; j < cnt; ++j) {
            float4 a = sT[j*4+0], b = sT[j*4+1], c = sT[j*4+2], e = sT[j*4+3];
            float dot = -(xn2p + sN[j]);
            dot = fmaf(x[0],  a.x, dot);
            dot = fmaf(x[1],  a.y, dot);
            dot = fmaf(x[2],  a.z, dot);
            dot = fmaf(x[3],  a.w, dot);
            dot = fmaf(x[4],  b.x, dot);
            dot = fmaf(x[5],  b.y, dot);
            dot = fmaf(x[6],  b.z, dot);
            dot = fmaf(x[7],  b.w, dot);
            dot = fmaf(x[8],  c.x, dot);
            dot = fmaf(x[9],  c.y, dot);
            dot = fmaf(x[10], c.z, dot);
            dot = fmaf(x[11], c.w, dot);
            dot = fmaf(x[12], e.x, dot);
            dot = fmaf(x[13], e.y, dot);
            dot = fmaf(x[14], e.z, dot);
            dot = fmaf(x[15], e.w, dot);
            acc += __builtin_amdgcn_exp2f(dot);
        }
    }

    if (valid) {
        if (writeFinal)
            wsOrOut[ti] = __logf(acc) - Z;
        else
            wsOrOut[blockIdx.y * nTest + ti] = acc;
    }
}

__global__ void kde_final(const float* __restrict__ ws, float* __restrict__ out,
                          int nTest, int S, float Z)
{
    int i = blockIdx.x * blockDim.x + threadIdx.x;
    if (i < nTest) {
        float s = 0.0f;
        for (int k = 0; k < S; ++k) s += ws[k * nTest + i];
        out[i] = __logf(s) - Z;
    }
}

extern "C" void kernel_launch(void* const* d_in, const int* in_sizes, int n_in,
                              void* d_out, int out_size, void* d_ws, size_t ws_size,
                              hipStream_t stream) {
    const float* testX  = (const float*)d_in[0];
    const float* trainX = (const float*)d_in[1];
    float* out = (float*)d_out;

    const int D = 16;
    const int nTest  = in_sizes[0] / D;   // 4096
    const int nTrain = in_sizes[1] / D;   // 8192

    // Z = 0.5*d*log(2*pi) + d*log(h=1) + log(n)
    const float Z = 0.5f * (float)D * logf(2.0f * (float)M_PI) + logf((float)nTrain);

    // Split train dim for parallelism; partials in d_ws (deterministic).
    int S = 32;
    while (S > 1 && (size_t)S * (size_t)nTest * sizeof(float) > ws_size) S >>= 1;
    if ((size_t)nTest * sizeof(float) > ws_size) S = 0;  // ws too small even for S=1

    const int gx = (nTest + 255) / 256;

    if (S <= 1) {
        // Direct path: each thread scans all train points, writes final out.
        dim3 grid(gx, 1);
        kde_partial<<<grid, 256, 0, stream>>>(testX, trainX, out,
                                              nTest, nTrain, nTrain, 1, Z);
    } else {
        const int trainPer = (nTrain + S - 1) / S;
        dim3 grid(gx, S);
        kde_partial<<<grid, 256, 0, stream>>>(testX, trainX, (float*)d_ws,
                                              nTest, nTrain, trainPer, 0, Z);
        kde_final<<<(nTest + 255) / 256, 256, 0, stream>>>((const float*)d_ws, out,
                                                           nTest, S, Z);
    }
}